// Round 11
// baseline (159.844 us; speedup 1.0000x reference)
//
#include <hip/hip_runtime.h>
#include <cstdint>
#include <cstddef>

// ---------------- problem constants ----------------
#define Bn   16
#define Cn   256
#define Nn   4096      // 16^3 spatial
#define Ln   77
#define LPn  80        // padded L rows (scores), 5 tiles of 16
#define LKn  96        // padded L for PV K-dim (3 k-steps of 32)
#define CTXn 768
#define Gn   32

typedef unsigned short u16;
typedef unsigned int   u32;
using frag8 = __attribute__((ext_vector_type(8))) short;   // 8 x bf16 (4 VGPR)
using f32x4 = __attribute__((ext_vector_type(4))) float;
using u16x4 = __attribute__((ext_vector_type(4))) u16;
using u16x8 = __attribute__((ext_vector_type(8))) u16;

__device__ __forceinline__ float b2f(u16 b) {
    union { u32 u; float f; } v; v.u = ((u32)b) << 16; return v.f;
}
__device__ __forceinline__ u16 f2b(float f) {  // RNE f32->bf16
    union { float f; u32 u; } v; v.f = f;
    u32 u = v.u;
    return (u16)((u + 0x7fffu + ((u >> 16) & 1u)) >> 16);
}
__device__ __forceinline__ u16x4 cast4(f32x4 s) {
    u16x4 p; p[0] = f2b(s[0]); p[1] = f2b(s[1]); p[2] = f2b(s[2]); p[3] = f2b(s[3]);
    return p;
}
// async global->LDS, 16B per lane. LDS dest must be lane-linear (base + lane*16).
__device__ __forceinline__ void gl16(const u16* g, u16* l) {
    __builtin_amdgcn_global_load_lds((const __attribute__((address_space(1))) u32*)g,
                                     (__attribute__((address_space(3))) u32*)l, 16, 0, 0);
}

// Chunked activation layout (per 64n tile): [kc(32)][row(64)] of 16B chunks (8 ch).
//   u16 index = (kc*64 + row)*8 + (c&7),  kc = c>>3, row = n&63.
// Chunked weight layout: [kc(32)][row(256)]: u16 idx = ((k>>3)*256 + r)*8 + (k&7).
// Chunked kt layout:     [b][kc(32)][l(80)]: u16 idx = b*20480 + ((c>>3)*80 + l)*8 + (c&7).

// ---------------- ws layout (bytes) ----------------
static const size_t OFF_T   = 33554432;             // bf16 chunked t [B][64][2048][8]
static const size_t OFF_CTXB = 33554432 - 2097152;  // bf16 [16][80][768] (dead before fused)
static const size_t OFF_KWB  = 35520512;            // bf16 [256][768] (dead after k_kv)
static const size_t OFF_VWB  = 35913728;            // bf16 [256][768] (dead after k_kv)
static const size_t OFF_KT  = 67108864;             // bf16 chunked [B][32][80][8] (40KB/b)
static const size_t OFF_V   = 67764224;             // bf16 [B][256][96]
static const size_t OFF_QWB = 68550656;             // bf16 chunked [32][256][8]
static const size_t OFF_OWB = 68681728;             // bf16 chunked [32][256][8]
static const size_t OFF_GS  = 68812800;             // f32 [B][32]
static const size_t OFF_GQ  = 68814848;             // f32 [B][32]
// kwb/vwb overlap t's region but die before k_fused writes t (stream-serialized).
// xbt (bf16 chunked x, 32MB) lives in d_out (fully overwritten by gnapply afterwards).

// ---------------- 1: merged prep: x transpose+cast (blocks 0..4095) +
//                    weight/ctx casts + GN zero (blocks 4096..5567) ----------------
__global__ void k_prepall(const float* __restrict__ x, u16* __restrict__ xbt,
                          const float* __restrict__ qw, const float* __restrict__ ow,
                          const float* __restrict__ kw, const float* __restrict__ vw,
                          const float* __restrict__ ctx,
                          u16* __restrict__ qwb, u16* __restrict__ owb,
                          u16* __restrict__ kwb, u16* __restrict__ vwb,
                          u16* __restrict__ ctxb, float* __restrict__ gz) {
    __shared__ float tile[64][65];
    int tid = threadIdx.x;
    if (blockIdx.x < 4096) {
        // x[b][c][n] f32 -> xbt chunked bf16. blk = nt + 64*(cq + 4*b)
        int blk = blockIdx.x;
        int nt = blk & 63, cq = (blk >> 6) & 3, b = blk >> 8;
        int c0 = cq * 64;
        int tr = tid >> 4, tc4 = (tid & 15) * 4;
#pragma unroll
        for (int i = 0; i < 4; ++i) {
            int cc = tr + i * 16;
            f32x4 vv = *(const f32x4*)(x + ((size_t)(b * Cn + c0 + cc)) * Nn + nt * 64 + tc4);
#pragma unroll
            for (int j = 0; j < 4; ++j) tile[cc][tc4 + j] = vv[j];
        }
        __syncthreads();
        int row = tid & 63, kq = tid >> 6;
        u16* xb = xbt + ((size_t)(b * 64 + nt)) * 16384;
#pragma unroll
        for (int it = 0; it < 2; ++it) {
            int kcl = kq + it * 4;                 // local chunk 0..7
            u16x8 pk;
#pragma unroll
            for (int j = 0; j < 8; ++j) pk[j] = f2b(tile[kcl * 8 + j][row]);
            *(u16x8*)(xb + (size_t)(((c0 >> 3) + kcl) * 64 + row) * 8) = pk;
        }
        return;
    }
    int i = (blockIdx.x - 4096) * 256 + tid;       // 376832 total
    if (i < 1024) gz[i] = 0.f;                     // gsum+gsq (4KB, contiguous)
    if (i < 16384) {
        int e = i * 4; int r = e >> 8; int k = e & 255;
        *(u16x4*)(qwb + ((size_t)((k >> 3) * 256 + r) * 8 + (k & 7))) =
            cast4(*(const f32x4*)(qw + e));
    } else if (i < 32768) {
        int e = (i - 16384) * 4; int r = e >> 8; int k = e & 255;
        *(u16x4*)(owb + ((size_t)((k >> 3) * 256 + r) * 8 + (k & 7))) =
            cast4(*(const f32x4*)(ow + e));
    } else if (i < 81920) {
        int j = i - 32768;
        *(u16x4*)(kwb + j * 4) = cast4(*(const f32x4*)(kw + j * 4));
    } else if (i < 131072) {
        int j = i - 81920;
        *(u16x4*)(vwb + j * 4) = cast4(*(const f32x4*)(vw + j * 4));
    } else {
        int j = i - 131072;                        // 0..245759
        int e = j * 4;
        int row = e / CTXn;                        // b*80 + l
        int d = e - row * CTXn;
        int b = row / LPn, l = row - b * LPn;
        u16x4 pk;
        if (l < Ln) {
            pk = cast4(*(const f32x4*)(ctx + ((size_t)(b * Ln + l)) * CTXn + d));
        } else {
            pk[0] = 0; pk[1] = 0; pk[2] = 0; pk[3] = 0;
        }
        *(u16x4*)(ctxb + e) = pk;
    }
}

// ---------------- 2: k/v projections via MFMA (kt stored chunked) ----------------
__launch_bounds__(256)
__global__ void k_kv(const u16* __restrict__ kwb, const u16* __restrict__ vwb,
                     const u16* __restrict__ ctxb, u16* __restrict__ kt,
                     u16* __restrict__ v) {
    int b = blockIdx.y;
    int tid = threadIdx.x;
    int wave = tid >> 6, lane = tid & 63;
    int l15 = lane & 15, q4 = lane >> 4;
    int c0 = blockIdx.x * 64 + wave * 16;
    const u16* cb = ctxb + (size_t)b * LPn * CTXn;

    f32x4 ak[5], av[5];
#pragma unroll
    for (int lt = 0; lt < 5; ++lt) {
        ak[lt] = (f32x4){0.f, 0.f, 0.f, 0.f};
        av[lt] = (f32x4){0.f, 0.f, 0.f, 0.f};
    }
    for (int ks = 0; ks < CTXn / 32; ++ks) {
        int kk = ks * 32 + 8 * q4;
        frag8 fk = *(const frag8*)(kwb + (size_t)(c0 + l15) * CTXn + kk);
        frag8 fv = *(const frag8*)(vwb + (size_t)(c0 + l15) * CTXn + kk);
#pragma unroll
        for (int lt = 0; lt < 5; ++lt) {
            frag8 fc = *(const frag8*)(cb + (size_t)(lt * 16 + l15) * CTXn + kk);
            ak[lt] = __builtin_amdgcn_mfma_f32_16x16x32_bf16(fk, fc, ak[lt], 0, 0, 0);
            av[lt] = __builtin_amdgcn_mfma_f32_16x16x32_bf16(fc, fv, av[lt], 0, 0, 0);
        }
    }
    int cc0 = c0 + q4 * 4;
    u16* ktb = kt + (size_t)b * 20480;
#pragma unroll
    for (int lt = 0; lt < 5; ++lt) {
        *(u16x4*)(ktb + (size_t)((cc0 >> 3) * LPn + lt * 16 + l15) * 8 + (cc0 & 7)) = cast4(ak[lt]);
        *(u16x4*)(v + ((size_t)(b * Cn + c0 + l15)) * LKn + lt * 16 + q4 * 4) = cast4(av[lt]);
    }
    u16x4 z; z[0] = 0; z[1] = 0; z[2] = 0; z[3] = 0;
    *(u16x4*)(v + ((size_t)(b * Cn + c0 + l15)) * LKn + 80 + q4 * 4) = z;
}

// ---------------- 3: FUSED q-proj -> QK^T -> softmax -> PV -> out-proj + GN ----------------
// One 64n tile per block, 4 waves. Single 32KB LDS buffer (x -> q -> h) + 13KB wl
// = 45KB -> 3 blocks/CU (12 waves). x staged async via gl16 from xbt; residual
// re-read from xbt in phase D. 5 barriers.
__launch_bounds__(256, 3)
__global__ void k_fused(const u16* __restrict__ qwb, const u16* __restrict__ owb,
                        const u16* __restrict__ xbt, const float* __restrict__ qb,
                        const float* __restrict__ obias,
                        const u16* __restrict__ ktg, const u16* __restrict__ vg,
                        u16* __restrict__ t, float* __restrict__ gsum,
                        float* __restrict__ gsq) {
    int nt = blockIdx.x, b = blockIdx.y;
    int tid = threadIdx.x;
    int w = tid >> 6, lane = tid & 63;
    int l15 = lane & 15, q4 = lane >> 4;

    __shared__ __align__(16) u16 sB[16384];     // x, then q, then h (chunked)
    __shared__ u16 wl[4][16][104];              // per-wave softmax weights

    const u16* xb = xbt + ((size_t)(b * 64 + nt)) * 16384;

    // ---- phase 0: async stage x tile (32KB) ----
#pragma unroll
    for (int j = 0; j < 8; ++j) {
        int c = j * 256 + tid;
        gl16(xb + (size_t)c * 8, &sB[(size_t)c * 8]);
    }
    __syncthreads();    // barrier 1: x resident

    // ---- phase A: q-GEMM (wave w owns o in [w*64, w*64+64)) ----
    f32x4 acc[4][4];
#pragma unroll
    for (int i = 0; i < 4; ++i)
#pragma unroll
        for (int j = 0; j < 4; ++j) acc[i][j] = (f32x4){0.f, 0.f, 0.f, 0.f};
#pragma unroll
    for (int ks = 0; ks < 8; ++ks) {
        frag8 bf[4];
#pragma unroll
        for (int n4 = 0; n4 < 4; ++n4)
            bf[n4] = *(const frag8*)&sB[(size_t)((ks * 4 + q4) * 64 + n4 * 16 + l15) * 8];
#pragma unroll
        for (int mt = 0; mt < 4; ++mt) {
            frag8 a = *(const frag8*)(qwb + (size_t)((ks * 4 + q4) * 256 + w * 64 + mt * 16 + l15) * 8);
#pragma unroll
            for (int n4 = 0; n4 < 4; ++n4)
                acc[mt][n4] = __builtin_amdgcn_mfma_f32_16x16x32_bf16(a, bf[n4], acc[mt][n4], 0, 0, 0);
        }
    }
    __syncthreads();    // barrier 2: all x reads done -> buffer reusable for q
    // q epilogue: D row = o (q4*4+r), col = n (l15) -> sB chunked (in place)
#pragma unroll
    for (int mt = 0; mt < 4; ++mt) {
        int o4 = w * 64 + mt * 16 + q4 * 4;
        f32x4 qb4 = *(const f32x4*)(qb + o4);
#pragma unroll
        for (int n4 = 0; n4 < 4; ++n4) {
            int row = n4 * 16 + l15;
            u16x4 pk;
#pragma unroll
            for (int r = 0; r < 4; ++r) pk[r] = f2b(acc[mt][n4][r] + qb4[r]);
            *(u16x4*)&sB[(size_t)((o4 >> 3) * 64 + row) * 8 + (o4 & 7)] = pk;
        }
    }
    __syncthreads();    // barrier 3: q complete

    // ---- phase B: QK^T (wave w owns n-rows [w*16, w*16+16)) + softmax ----
    int rw = w * 16;
    const u16* ktb = ktg + (size_t)b * 20480;
    f32x4 s5[5];
#pragma unroll
    for (int mt = 0; mt < 5; ++mt) s5[mt] = (f32x4){0.f, 0.f, 0.f, 0.f};
#pragma unroll
    for (int ks = 0; ks < 8; ++ks) {
        frag8 bq = *(const frag8*)&sB[(size_t)((ks * 4 + q4) * 64 + rw + l15) * 8];
#pragma unroll
        for (int mt = 0; mt < 5; ++mt) {
            frag8 ak = *(const frag8*)(ktb + (size_t)((ks * 4 + q4) * 80 + mt * 16 + l15) * 8);
            s5[mt] = __builtin_amdgcn_mfma_f32_16x16x32_bf16(ak, bq, s5[mt], 0, 0, 0);
        }
    }
    // softmax: lane n = l15, l = mt*16 + q4*4 + r
    {
        float m = -3e38f;
#pragma unroll
        for (int mt = 0; mt < 5; ++mt)
#pragma unroll
            for (int r = 0; r < 4; ++r) {
                int l = mt * 16 + q4 * 4 + r;
                if (l < Ln) m = fmaxf(m, s5[mt][r]);
            }
        m = fmaxf(m, __shfl_xor(m, 16));
        m = fmaxf(m, __shfl_xor(m, 32));
        float p[5][4];
        float sum = 0.f;
#pragma unroll
        for (int mt = 0; mt < 5; ++mt)
#pragma unroll
            for (int r = 0; r < 4; ++r) {
                int l = mt * 16 + q4 * 4 + r;
                float e = (l < Ln) ? __expf(s5[mt][r] - m) : 0.f;
                p[mt][r] = e;
                sum += e;
            }
        sum += __shfl_xor(sum, 16);
        sum += __shfl_xor(sum, 32);
        float inv = 1.f / sum;

        u32* wz = (u32*)&wl[w][0][0];           // 832 u32, per-wave region
#pragma unroll
        for (int i = 0; i < 13; ++i) wz[lane + i * 64] = 0;
#pragma unroll
        for (int mt = 0; mt < 5; ++mt)
#pragma unroll
            for (int r = 0; r < 4; ++r) {
                int l = mt * 16 + q4 * 4 + r;
                if (l < Ln) wl[w][l15][l] = f2b(p[mt][r] * inv);
            }
    }
    __syncthreads();    // barrier 4: all q reads done -> buffer reusable for h

    // ---- phase C: PV, swapped operands (D row = c -> u16x4 chunked writes) ----
    {
        frag8 fw[3];
#pragma unroll
        for (int ks = 0; ks < 3; ++ks)
            fw[ks] = *(const frag8*)(&wl[w][l15][ks * 32 + 8 * q4]);
        const u16* vb = vg + (size_t)b * Cn * LKn;
#pragma unroll
        for (int ct = 0; ct < 16; ++ct) {
            f32x4 h = (f32x4){0.f, 0.f, 0.f, 0.f};
#pragma unroll
            for (int ks = 0; ks < 3; ++ks) {
                frag8 fv = *(const frag8*)(vb + (size_t)(ct * 16 + l15) * LKn + ks * 32 + 8 * q4);
                h = __builtin_amdgcn_mfma_f32_16x16x32_bf16(fv, fw[ks], h, 0, 0, 0);
            }
            // c = ct*16 + q4*4 + r (4 consecutive), n = rw + l15
            *(u16x4*)&sB[(size_t)((ct * 2 + (q4 >> 1)) * 64 + rw + l15) * 8 + (q4 & 1) * 4] = cast4(h);
        }
    }
    __syncthreads();    // barrier 5: h complete

    // ---- phase D: out-GEMM + bias + residual(xbt) + chunked t store + GN partials ----
    {
        f32x4 dcc[4][4];
#pragma unroll
        for (int i = 0; i < 4; ++i)
#pragma unroll
            for (int j = 0; j < 4; ++j) dcc[i][j] = (f32x4){0.f, 0.f, 0.f, 0.f};
#pragma unroll
        for (int ks = 0; ks < 8; ++ks) {
            frag8 bf[4];
#pragma unroll
            for (int n4 = 0; n4 < 4; ++n4)
                bf[n4] = *(const frag8*)&sB[(size_t)((ks * 4 + q4) * 64 + n4 * 16 + l15) * 8];
#pragma unroll
            for (int mt = 0; mt < 4; ++mt) {
                frag8 a = *(const frag8*)(owb + (size_t)((ks * 4 + q4) * 256 + w * 64 + mt * 16 + l15) * 8);
#pragma unroll
                for (int n4 = 0; n4 < 4; ++n4)
                    dcc[mt][n4] = __builtin_amdgcn_mfma_f32_16x16x32_bf16(a, bf[n4], dcc[mt][n4], 0, 0, 0);
            }
        }
        u16* tb = t + ((size_t)(b * 64 + nt)) * 16384;
        float gps[4] = {0.f, 0.f, 0.f, 0.f}, gpq[4] = {0.f, 0.f, 0.f, 0.f};
#pragma unroll
        for (int mt = 0; mt < 4; ++mt) {
            int o4 = w * 64 + mt * 16 + q4 * 4;
            f32x4 ob4 = *(const f32x4*)(obias + o4);
            size_t kcb = (size_t)(o4 >> 3) * 64;
            int off = o4 & 7;
#pragma unroll
            for (int n4 = 0; n4 < 4; ++n4) {
                int row = n4 * 16 + l15;
                size_t idx = (kcb + row) * 8 + off;
                u16x4 xv = *(const u16x4*)(xb + idx);   // residual from global xbt
                u16x4 pk;
#pragma unroll
                for (int r = 0; r < 4; ++r) {
                    float val = dcc[mt][n4][r] + ob4[r] + b2f(xv[r]);
                    pk[r] = f2b(val);
                    gps[mt] += val; gpq[mt] += val * val;
                }
                *(u16x4*)(tb + idx) = pk;
            }
        }
        // GN reduce: lane's 4 vals in group g = w*8 + mt*2 + (q4>>1)
#pragma unroll
        for (int mt = 0; mt < 4; ++mt) {
            float s = gps[mt], q = gpq[mt];
            s += __shfl_xor(s, 1);  q += __shfl_xor(q, 1);
            s += __shfl_xor(s, 2);  q += __shfl_xor(q, 2);
            s += __shfl_xor(s, 4);  q += __shfl_xor(q, 4);
            s += __shfl_xor(s, 8);  q += __shfl_xor(q, 8);
            s += __shfl_xor(s, 16); q += __shfl_xor(q, 16);
            if ((lane & 31) == 0) {   // lane 0 (q4 0/1) or lane 32 (q4 2/3)
                int g = w * 8 + mt * 2 + (lane >> 5);
                atomicAdd(&gsum[b * Gn + g], s);
                atomicAdd(&gsq[b * Gn + g], q);
            }
        }
    }
}

// ---------------- 4: GroupNorm apply + Swish (chunked t -> [b][c][n] f32 out) ----------------
__launch_bounds__(256)
__global__ void k_gnapply(const u16* __restrict__ t, const float* __restrict__ gsum,
                          const float* __restrict__ gsq, const float* __restrict__ gamma,
                          const float* __restrict__ beta, float* __restrict__ out) {
    int nt = blockIdx.x, b = blockIdx.y;
    __shared__ __align__(16) u16 s[16384];          // 32KB tile
    const u16* tb = t + ((size_t)(b * 64 + nt)) * 16384;
    int tid = threadIdx.x;
#pragma unroll
    for (int j = 0; j < 8; ++j) {
        int c = j * 256 + tid;
        gl16(tb + (size_t)c * 8, &s[(size_t)c * 8]);
    }
    int c8 = tid >> 3, n8 = tid & 7;                // group g = c8, n-base = n8*8
    float mean = gsum[b * Gn + c8] * (1.0f / 32768.f);
    float var = gsq[b * Gn + c8] * (1.0f / 32768.f) - mean * mean;
    float rstd = rsqrtf(var + 1e-5f);
    __syncthreads();
    u16x8 v[8];
#pragma unroll
    for (int j = 0; j < 8; ++j)
        v[j] = *(const u16x8*)&s[(size_t)(c8 * 64 + n8 * 8 + j) * 8];
    float* ob = out + ((size_t)(b * Cn + c8 * 8)) * Nn + nt * 64 + n8 * 8;
#pragma unroll
    for (int cc = 0; cc < 8; ++cc) {
        float ga = gamma[c8 * 8 + cc], be = beta[c8 * 8 + cc];
        f32x4 lo, hi;
#pragma unroll
        for (int j = 0; j < 4; ++j) {
            float hv = (b2f(v[j][cc]) - mean) * rstd * ga + be;
            lo[j] = hv / (1.f + __expf(-hv));
        }
#pragma unroll
        for (int j = 0; j < 4; ++j) {
            float hv = (b2f(v[j + 4][cc]) - mean) * rstd * ga + be;
            hi[j] = hv / (1.f + __expf(-hv));
        }
        *(f32x4*)(ob + (size_t)cc * Nn) = lo;
        *(f32x4*)(ob + (size_t)cc * Nn + 4) = hi;
    }
}

// ---------------- launcher ----------------
extern "C" void kernel_launch(void* const* d_in, const int* in_sizes, int n_in,
                              void* d_out, int out_size, void* d_ws, size_t ws_size,
                              hipStream_t stream) {
    (void)in_sizes; (void)n_in; (void)out_size; (void)ws_size;
    const float* x     = (const float*)d_in[0];
    const float* ctx   = (const float*)d_in[1];
    const float* qw    = (const float*)d_in[2];
    const float* qb    = (const float*)d_in[3];
    const float* kw    = (const float*)d_in[4];
    const float* vw    = (const float*)d_in[5];
    const float* ow    = (const float*)d_in[6];
    const float* ob    = (const float*)d_in[7];
    const float* gamma = (const float*)d_in[8];
    const float* beta  = (const float*)d_in[9];
    float* out = (float*)d_out;
    char* ws = (char*)d_ws;

    u16* t    = (u16*)(ws + OFF_T);
    u16* ctxb = (u16*)(ws + OFF_CTXB);
    u16* kwb  = (u16*)(ws + OFF_KWB);
    u16* vwb  = (u16*)(ws + OFF_VWB);
    u16* kt   = (u16*)(ws + OFF_KT);
    u16* v    = (u16*)(ws + OFF_V);
    u16* qwb  = (u16*)(ws + OFF_QWB);
    u16* owb  = (u16*)(ws + OFF_OWB);
    float* gsum = (float*)(ws + OFF_GS);
    float* gsq  = (float*)(ws + OFF_GQ);
    u16* xbt = (u16*)d_out;           // 32MB scratch in out (overwritten by gnapply)

    k_prepall<<<5568, 256, 0, stream>>>(x, xbt, qw, ow, kw, vw, ctx,
                                        qwb, owb, kwb, vwb, ctxb, gsum);
    k_kv<<<dim3(4, Bn), 256, 0, stream>>>(kwb, vwb, ctxb, kt, v);
    k_fused<<<dim3(64, Bn), 256, 0, stream>>>(qwb, owb, xbt, qb, ob, kt, v, t, gsum, gsq);
    k_gnapply<<<dim3(64, Bn), 256, 0, stream>>>(t, gsum, gsq, gamma, beta, out);
}

// Round 12
// 120.759 us; speedup vs baseline: 1.3237x; 1.3237x over previous
//
#include <hip/hip_runtime.h>
#include <cstdint>
#include <cstddef>

// ---------------- problem constants ----------------
#define Bn   16
#define Cn   256
#define Nn   4096      // 16^3 spatial
#define Ln   77
#define LPn  80        // padded L rows (scores), 5 tiles of 16
#define LKn  96        // padded L for the collapsed PV/out GEMM K-dim (3 k-steps of 32)
#define CTXn 768
#define Gn   32

typedef unsigned short u16;
typedef unsigned int   u32;
using frag8 = __attribute__((ext_vector_type(8))) short;   // 8 x bf16 (4 VGPR)
using f32x4 = __attribute__((ext_vector_type(4))) float;
using u16x4 = __attribute__((ext_vector_type(4))) u16;
using u16x8 = __attribute__((ext_vector_type(8))) u16;

__device__ __forceinline__ float b2f(u16 b) {
    union { u32 u; float f; } v; v.u = ((u32)b) << 16; return v.f;
}
__device__ __forceinline__ u16 f2b(float f) {  // RNE f32->bf16
    union { float f; u32 u; } v; v.f = f;
    u32 u = v.u;
    return (u16)((u + 0x7fffu + ((u >> 16) & 1u)) >> 16);
}
__device__ __forceinline__ u16x4 cast4(f32x4 s) {
    u16x4 p; p[0] = f2b(s[0]); p[1] = f2b(s[1]); p[2] = f2b(s[2]); p[3] = f2b(s[3]);
    return p;
}
// async global->LDS, 16B per lane. LDS dest must be lane-linear (base + lane*16).
__device__ __forceinline__ void gl16(const u16* g, u16* l) {
    __builtin_amdgcn_global_load_lds((const __attribute__((address_space(1))) u32*)g,
                                     (__attribute__((address_space(3))) u32*)l, 16, 0, 0);
}

// Chunked activation layout (per 64n tile): [kc(32)][row(64)] of 16B chunks (8 ch).
//   u16 index = (kc*64 + row)*8 + (c&7),  kc = c>>3, row = n&63.
// Chunked weight layout [in-c chunks]: idx = ((k>>3)*256 + r)*8 + (k&7).
// kt chunked:  [b][c-chunk(32)][l(80)][8]  (40KB/b)
// kq chunked:  [b][c-chunk(32)][l(80)][8]  (40KB/b)  kq[l][c] = sum_c' kt[l][c']*qw[c'][c]
// vo chunked:  [b][l-chunk(12)][o(256)][8] (48KB/b)  vo[o][l] = sum_c ow[o][c]*v[c][l]
// vc row-major:[b][l(96)][c(256)]          (48KB/b)  vc[l][c] = v[c][l], rows >=77 zero

// ---------------- ws layout (bytes) ----------------
static const size_t OFF_T    = 33554432;            // bf16 chunked t [B][64][2048][8]
static const size_t OFF_CTXB = 31457280;            // bf16 [16][80][768] (dead after k_kv)
static const size_t OFF_KQ   = 31457280;            // overlays dead ctxb (written by k_kqvo)
static const size_t OFF_VO   = 32112640;            // + 655360
static const size_t OFF_KQB  = 32899072;            // + 786432 (f32 [16][80])
static const size_t OFF_KWB  = 35520512;            // bf16 [256][768] (dead after k_kv)
static const size_t OFF_VWB  = 35913728;            // bf16 [256][768] (dead after k_kv)
static const size_t OFF_KT   = 67108864;            // kt chunked
static const size_t OFF_V    = 67764224;            // vc row-major [96][256] per b
static const size_t OFF_QWB  = 68550656;            // qwTb chunked [c'-chunk][c][8]
static const size_t OFF_OWB  = 68681728;            // owb chunked [c-chunk][o][8]
static const size_t OFF_GS   = 68812800;            // f32 [B][32]
static const size_t OFF_GQ   = 68814848;            // f32 [B][32]
// kwb/vwb overlap t's region but die before k_fused2 writes t (stream-serialized).
// xbt (bf16 chunked x, 32MB) lives in d_out (fully overwritten by gnapply afterwards).

// ---------------- 1: merged prep: x transpose+cast (blocks 0..4095) +
//                    weight/ctx casts + GN zero (blocks 4096..5567) ----------------
__global__ void k_prepall(const float* __restrict__ x, u16* __restrict__ xbt,
                          const float* __restrict__ qw, const float* __restrict__ ow,
                          const float* __restrict__ kw, const float* __restrict__ vw,
                          const float* __restrict__ ctx,
                          u16* __restrict__ qwTb, u16* __restrict__ owb,
                          u16* __restrict__ kwb, u16* __restrict__ vwb,
                          u16* __restrict__ ctxb, float* __restrict__ gz) {
    __shared__ float tile[64][65];
    int tid = threadIdx.x;
    if (blockIdx.x < 4096) {
        // x[b][c][n] f32 -> xbt chunked bf16. blk = nt + 64*(cq + 4*b)
        int blk = blockIdx.x;
        int nt = blk & 63, cq = (blk >> 6) & 3, b = blk >> 8;
        int c0 = cq * 64;
        int tr = tid >> 4, tc4 = (tid & 15) * 4;
#pragma unroll
        for (int i = 0; i < 4; ++i) {
            int cc = tr + i * 16;
            f32x4 vv = *(const f32x4*)(x + ((size_t)(b * Cn + c0 + cc)) * Nn + nt * 64 + tc4);
#pragma unroll
            for (int j = 0; j < 4; ++j) tile[cc][tc4 + j] = vv[j];
        }
        __syncthreads();
        int row = tid & 63, kq_ = tid >> 6;
        u16* xb = xbt + ((size_t)(b * 64 + nt)) * 16384;
#pragma unroll
        for (int it = 0; it < 2; ++it) {
            int kcl = kq_ + it * 4;                // local chunk 0..7
            u16x8 pk;
#pragma unroll
            for (int j = 0; j < 8; ++j) pk[j] = f2b(tile[kcl * 8 + j][row]);
            *(u16x8*)(xb + (size_t)(((c0 >> 3) + kcl) * 64 + row) * 8) = pk;
        }
        return;
    }
    int i = (blockIdx.x - 4096) * 256 + tid;       // 376832 total
    if (i < 1024) gz[i] = 0.f;                     // gsum+gsq (4KB, contiguous)
    if (i < 16384) {
        // qw [c'][c] -> qwTb chunked: idx = ((c'>>3)*256 + c)*8 + (c'&7)
        int e = i * 4; int cp = e >> 8; int c = e & 255;
        f32x4 v4 = *(const f32x4*)(qw + e);
#pragma unroll
        for (int j = 0; j < 4; ++j)
            qwTb[(size_t)((cp >> 3) * 256 + c + j) * 8 + (cp & 7)] = f2b(v4[j]);
    } else if (i < 32768) {
        // ow [o][c] -> owb chunked: idx = ((c>>3)*256 + o)*8 + (c&7)
        int e = (i - 16384) * 4; int r = e >> 8; int k = e & 255;
        *(u16x4*)(owb + ((size_t)((k >> 3) * 256 + r) * 8 + (k & 7))) =
            cast4(*(const f32x4*)(ow + e));
    } else if (i < 81920) {
        int j = i - 32768;
        *(u16x4*)(kwb + j * 4) = cast4(*(const f32x4*)(kw + j * 4));
    } else if (i < 131072) {
        int j = i - 81920;
        *(u16x4*)(vwb + j * 4) = cast4(*(const f32x4*)(vw + j * 4));
    } else {
        int j = i - 131072;                        // 0..245759
        int e = j * 4;
        int row = e / CTXn;                        // b*80 + l
        int d = e - row * CTXn;
        int b = row / LPn, l = row - b * LPn;
        u16x4 pk;
        if (l < Ln) {
            pk = cast4(*(const f32x4*)(ctx + ((size_t)(b * Ln + l)) * CTXn + d));
        } else {
            pk[0] = 0; pk[1] = 0; pk[2] = 0; pk[3] = 0;
        }
        *(u16x4*)(ctxb + e) = pk;
    }
}

// ---------------- 2: k/v projections via MFMA (kt chunked, vc row-major) ----------------
__launch_bounds__(256)
__global__ void k_kv(const u16* __restrict__ kwb, const u16* __restrict__ vwb,
                     const u16* __restrict__ ctxb, u16* __restrict__ kt,
                     u16* __restrict__ vc) {
    int b = blockIdx.y;
    int tid = threadIdx.x;
    int wave = tid >> 6, lane = tid & 63;
    int l15 = lane & 15, q4 = lane >> 4;
    int c0 = blockIdx.x * 64 + wave * 16;
    const u16* cb = ctxb + (size_t)b * LPn * CTXn;

    f32x4 ak[5], av[5];
#pragma unroll
    for (int lt = 0; lt < 5; ++lt) {
        ak[lt] = (f32x4){0.f, 0.f, 0.f, 0.f};
        av[lt] = (f32x4){0.f, 0.f, 0.f, 0.f};
    }
    for (int ks = 0; ks < CTXn / 32; ++ks) {
        int kk = ks * 32 + 8 * q4;
        frag8 fk = *(const frag8*)(kwb + (size_t)(c0 + l15) * CTXn + kk);
        frag8 fv = *(const frag8*)(vwb + (size_t)(c0 + l15) * CTXn + kk);
#pragma unroll
        for (int lt = 0; lt < 5; ++lt) {
            frag8 fc = *(const frag8*)(cb + (size_t)(lt * 16 + l15) * CTXn + kk);
            ak[lt] = __builtin_amdgcn_mfma_f32_16x16x32_bf16(fk, fc, ak[lt], 0, 0, 0);
            av[lt] = __builtin_amdgcn_mfma_f32_16x16x32_bf16(fc, fv, av[lt], 0, 0, 0);
        }
    }
    // kt chunked: ak D row = c (q4*4..+3), col = l (l15)
    int cc0 = c0 + q4 * 4;
    u16* ktb = kt + (size_t)b * 20480;
    u16* vcb = vc + (size_t)b * 24576;
#pragma unroll
    for (int lt = 0; lt < 5; ++lt) {
        *(u16x4*)(ktb + (size_t)((cc0 >> 3) * LPn + lt * 16 + l15) * 8 + (cc0 & 7)) = cast4(ak[lt]);
        // vc[l][c]: av D row = l (q4*4+r), col = c (l15)
#pragma unroll
        for (int r = 0; r < 4; ++r)
            vcb[(size_t)(lt * 16 + q4 * 4 + r) * 256 + c0 + l15] = f2b(av[lt][r]);
    }
    // zero vc rows 80..95 for this block's 64 c
    int cb0 = blockIdx.x * 64;
    for (int idx = tid; idx < 16 * 64; idx += 256)
        vcb[(size_t)(80 + (idx >> 6)) * 256 + cb0 + (idx & 63)] = 0;
}

// ---------------- 3: kq / kqb / vo precompute ----------------
// bx<4:  kq[l][c] = sum_c' kt[l][c'] * qw[c'][c]   (c-slice 64 per block)
//        + (bx==0) kqb[l] = sum_c' qb[c'] * kt[l][c']
// bx>=4: vo[o][l] = sum_c ow[o][c] * v[c][l]       (o-slice 64 per block)
__launch_bounds__(256)
__global__ void k_kqvo(const u16* __restrict__ kt, const u16* __restrict__ qwTb,
                       const u16* __restrict__ owb, const u16* __restrict__ vc,
                       const float* __restrict__ qb, u16* __restrict__ kq,
                       float* __restrict__ kqb, u16* __restrict__ vo) {
    int bx = blockIdx.x, b = blockIdx.y;
    int tid = threadIdx.x;
    int w = tid >> 6, lane = tid & 63;
    int l15 = lane & 15, q4 = lane >> 4;
    const u16* ktb = kt + (size_t)b * 20480;

    if (bx < 4) {
        int c = bx * 64 + w * 16 + l15;            // output col (free channel)
        f32x4 acc[5];
#pragma unroll
        for (int lt = 0; lt < 5; ++lt) acc[lt] = (f32x4){0.f, 0.f, 0.f, 0.f};
#pragma unroll
        for (int ks = 0; ks < 8; ++ks) {
            frag8 bqw = *(const frag8*)(qwTb + (size_t)((ks * 4 + q4) * 256 + c) * 8);
#pragma unroll
            for (int lt = 0; lt < 5; ++lt) {
                frag8 akt = *(const frag8*)(ktb + (size_t)((ks * 4 + q4) * 80 + lt * 16 + l15) * 8);
                acc[lt] = __builtin_amdgcn_mfma_f32_16x16x32_bf16(akt, bqw, acc[lt], 0, 0, 0);
            }
        }
        u16* kqB = kq + (size_t)b * 20480;
#pragma unroll
        for (int lt = 0; lt < 5; ++lt)
#pragma unroll
            for (int r = 0; r < 4; ++r) {
                int l = lt * 16 + q4 * 4 + r;
                kqB[(size_t)((c >> 3) * 80 + l) * 8 + (c & 7)] = f2b(acc[lt][r]);
            }
        if (bx == 0 && tid < 80) {
            float s = 0.f;
            for (int kc = 0; kc < 32; ++kc) {
                u16x8 kv8 = *(const u16x8*)(ktb + (size_t)(kc * 80 + tid) * 8);
#pragma unroll
                for (int j = 0; j < 8; ++j) s += b2f(kv8[j]) * qb[kc * 8 + j];
            }
            kqb[b * 80 + tid] = s;
        }
    } else {
        int ob = (bx - 4) * 64 + w * 16;           // o-tile base (rows)
        const u16* vcb = vc + (size_t)b * 24576;
        f32x4 acc[6];
#pragma unroll
        for (int lt = 0; lt < 6; ++lt) acc[lt] = (f32x4){0.f, 0.f, 0.f, 0.f};
#pragma unroll
        for (int ks = 0; ks < 8; ++ks) {
            frag8 aow = *(const frag8*)(owb + (size_t)((ks * 4 + q4) * 256 + ob + l15) * 8);
#pragma unroll
            for (int lt = 0; lt < 6; ++lt) {
                frag8 bvc = *(const frag8*)(vcb + (size_t)(lt * 16 + l15) * 256 + ks * 32 + q4 * 8);
                acc[lt] = __builtin_amdgcn_mfma_f32_16x16x32_bf16(aow, bvc, acc[lt], 0, 0, 0);
            }
        }
        u16* voB = vo + (size_t)b * 24576;
#pragma unroll
        for (int lt = 0; lt < 6; ++lt) {
            int l = lt * 16 + l15;                 // D col = l
#pragma unroll
            for (int r = 0; r < 4; ++r) {
                int o = ob + q4 * 4 + r;           // D row = o
                voB[(size_t)((l >> 3) * 256 + o) * 8 + (l & 7)] = f2b(acc[lt][r]);
            }
        }
    }
}

// ---------------- 4: FUSED scores -> softmax -> t-GEMM + residual + GN ----------------
// One 64n tile per block, 4 waves, ONE barrier. LDS = 12KB (w only).
// scores^T[l][n] = sum_c kq[l][c]*x[n][c] + kqb[l]   (wave w owns n-rows w*16..+16)
// t[o][n] = sum_l vo[o][l]*w[n][l] + ob[o] + x[o][n] (wave w owns o-slice w*64..+64)
__launch_bounds__(256, 3)
__global__ void k_fused2(const u16* __restrict__ kq, const u16* __restrict__ vo,
                         const float* __restrict__ kqb, const u16* __restrict__ xbt,
                         const float* __restrict__ obias, u16* __restrict__ t,
                         float* __restrict__ gsum, float* __restrict__ gsq) {
    int nt = blockIdx.x, b = blockIdx.y;
    int tid = threadIdx.x;
    int w = tid >> 6, lane = tid & 63;
    int l15 = lane & 15, q4 = lane >> 4;
    int rw = w * 16;

    __shared__ __align__(16) u16 wl[12 * 64 * 8];   // w chunked [lc(12)][n(64)][8], 12KB

    const u16* xb = xbt + ((size_t)(b * 64 + nt)) * 16384;

    // zero own rows of the l>=80 pad chunks (kc 10,11) — wave-local, no barrier
    {
        u32* wz = (u32*)wl;
        int kcq = lane >> 5, rr = (lane >> 1) & 15, wd = (lane & 1) * 2;
        int base = ((10 + kcq) * 64 + rw + rr) * 4 + wd;
        wz[base] = 0; wz[base + 1] = 0;
    }

    // ---- scores + softmax (wave-local) ----
    const u16* kqB = kq + (size_t)b * 20480;
    f32x4 s5[5];
#pragma unroll
    for (int lt = 0; lt < 5; ++lt) s5[lt] = (f32x4){0.f, 0.f, 0.f, 0.f};
#pragma unroll
    for (int ks = 0; ks < 8; ++ks) {
        frag8 bq = *(const frag8*)(xb + (size_t)((ks * 4 + q4) * 64 + rw + l15) * 8);
#pragma unroll
        for (int lt = 0; lt < 5; ++lt) {
            frag8 akq = *(const frag8*)(kqB + (size_t)((ks * 4 + q4) * 80 + lt * 16 + l15) * 8);
            s5[lt] = __builtin_amdgcn_mfma_f32_16x16x32_bf16(akq, bq, s5[lt], 0, 0, 0);
        }
    }
    const float* kqbB = kqb + b * 80;
#pragma unroll
    for (int lt = 0; lt < 5; ++lt) {
        f32x4 bb = *(const f32x4*)(kqbB + lt * 16 + q4 * 4);
        s5[lt] += bb;
    }
    // lane: n = l15 (within wave rows), l = lt*16 + q4*4 + r. Softmax over l.
    {
        float m = -3e38f;
#pragma unroll
        for (int lt = 0; lt < 5; ++lt)
#pragma unroll
            for (int r = 0; r < 4; ++r) {
                int l = lt * 16 + q4 * 4 + r;
                if (l < Ln) m = fmaxf(m, s5[lt][r]);
            }
        m = fmaxf(m, __shfl_xor(m, 16));
        m = fmaxf(m, __shfl_xor(m, 32));
        float p[5][4];
        float sum = 0.f;
#pragma unroll
        for (int lt = 0; lt < 5; ++lt)
#pragma unroll
            for (int r = 0; r < 4; ++r) {
                int l = lt * 16 + q4 * 4 + r;
                float e = (l < Ln) ? __expf(s5[lt][r] - m) : 0.f;
                p[lt][r] = e;
                sum += e;
            }
        sum += __shfl_xor(sum, 16);
        sum += __shfl_xor(sum, 32);
        float inv = 1.f / sum;
        // store w chunked: [l4>>3][rw+l15][8] + (l4&7); p already zero for l>=77
#pragma unroll
        for (int lt = 0; lt < 5; ++lt) {
            int l4 = lt * 16 + q4 * 4;
            u16x4 pk;
#pragma unroll
            for (int r = 0; r < 4; ++r) pk[r] = f2b(p[lt][r] * inv);
            *(u16x4*)&wl[(size_t)((l4 >> 3) * 64 + rw + l15) * 8 + (l4 & 7)] = pk;
        }
    }
    __syncthreads();    // single barrier: w complete across waves

    // ---- t-GEMM (K = 96): t[o][n] = sum_l vo[o][l] * w[n][l] ----
    const u16* voB = vo + (size_t)b * 24576;
    f32x4 dcc[4][4];
#pragma unroll
    for (int i = 0; i < 4; ++i)
#pragma unroll
        for (int j = 0; j < 4; ++j) dcc[i][j] = (f32x4){0.f, 0.f, 0.f, 0.f};
#pragma unroll
    for (int ks = 0; ks < 3; ++ks) {
        frag8 wf[4];
#pragma unroll
        for (int n4 = 0; n4 < 4; ++n4)
            wf[n4] = *(const frag8*)&wl[(size_t)((ks * 4 + q4) * 64 + n4 * 16 + l15) * 8];
#pragma unroll
        for (int mt = 0; mt < 4; ++mt) {
            frag8 af = *(const frag8*)(voB + (size_t)((ks * 4 + q4) * 256 + w * 64 + mt * 16 + l15) * 8);
#pragma unroll
            for (int n4 = 0; n4 < 4; ++n4)
                dcc[mt][n4] = __builtin_amdgcn_mfma_f32_16x16x32_bf16(af, wf[n4], dcc[mt][n4], 0, 0, 0);
        }
    }
    // epilogue: D row = o (q4*4+r), col = n (l15). residual from xbt, t chunked store.
    u16* tb = t + ((size_t)(b * 64 + nt)) * 16384;
    float gps[4] = {0.f, 0.f, 0.f, 0.f}, gpq[4] = {0.f, 0.f, 0.f, 0.f};
#pragma unroll
    for (int mt = 0; mt < 4; ++mt) {
        int o4 = w * 64 + mt * 16 + q4 * 4;
        f32x4 ob4 = *(const f32x4*)(obias + o4);
        size_t kcb = (size_t)(o4 >> 3) * 64;
        int off = o4 & 7;
#pragma unroll
        for (int n4 = 0; n4 < 4; ++n4) {
            int row = n4 * 16 + l15;
            size_t idx = (kcb + row) * 8 + off;
            u16x4 xv = *(const u16x4*)(xb + idx);
            u16x4 pk;
#pragma unroll
            for (int r = 0; r < 4; ++r) {
                float val = dcc[mt][n4][r] + ob4[r] + b2f(xv[r]);
                pk[r] = f2b(val);
                gps[mt] += val; gpq[mt] += val * val;
            }
            *(u16x4*)(tb + idx) = pk;
        }
    }
    // GN reduce: lane's 4 vals in group g = w*8 + mt*2 + (q4>>1)
#pragma unroll
    for (int mt = 0; mt < 4; ++mt) {
        float s = gps[mt], q = gpq[mt];
        s += __shfl_xor(s, 1);  q += __shfl_xor(q, 1);
        s += __shfl_xor(s, 2);  q += __shfl_xor(q, 2);
        s += __shfl_xor(s, 4);  q += __shfl_xor(q, 4);
        s += __shfl_xor(s, 8);  q += __shfl_xor(q, 8);
        s += __shfl_xor(s, 16); q += __shfl_xor(q, 16);
        if ((lane & 31) == 0) {   // lane 0 (q4 0/1) or lane 32 (q4 2/3)
            int g = w * 8 + mt * 2 + (lane >> 5);
            atomicAdd(&gsum[b * Gn + g], s);
            atomicAdd(&gsq[b * Gn + g], q);
        }
    }
}

// ---------------- 5: GroupNorm apply + Swish (chunked t -> [b][c][n] f32 out) ----------------
__launch_bounds__(256)
__global__ void k_gnapply(const u16* __restrict__ t, const float* __restrict__ gsum,
                          const float* __restrict__ gsq, const float* __restrict__ gamma,
                          const float* __restrict__ beta, float* __restrict__ out) {
    int nt = blockIdx.x, b = blockIdx.y;
    __shared__ __align__(16) u16 s[16384];          // 32KB tile
    const u16* tb = t + ((size_t)(b * 64 + nt)) * 16384;
    int tid = threadIdx.x;
#pragma unroll
    for (int j = 0; j < 8; ++j) {
        int c = j * 256 + tid;
        gl16(tb + (size_t)c * 8, &s[(size_t)c * 8]);
    }
    int c8 = tid >> 3, n8 = tid & 7;                // group g = c8, n-base = n8*8
    float mean = gsum[b * Gn + c8] * (1.0f / 32768.f);
    float var = gsq[b * Gn + c8] * (1.0f / 32768.f) - mean * mean;
    float rstd = rsqrtf(var + 1e-5f);
    __syncthreads();
    u16x8 v[8];
#pragma unroll
    for (int j = 0; j < 8; ++j)
        v[j] = *(const u16x8*)&s[(size_t)(c8 * 64 + n8 * 8 + j) * 8];
    float* ob = out + ((size_t)(b * Cn + c8 * 8)) * Nn + nt * 64 + n8 * 8;
#pragma unroll
    for (int cc = 0; cc < 8; ++cc) {
        float ga = gamma[c8 * 8 + cc], be = beta[c8 * 8 + cc];
        f32x4 lo, hi;
#pragma unroll
        for (int j = 0; j < 4; ++j) {
            float hv = (b2f(v[j][cc]) - mean) * rstd * ga + be;
            lo[j] = hv / (1.f + __expf(-hv));
        }
#pragma unroll
        for (int j = 0; j < 4; ++j) {
            float hv = (b2f(v[j + 4][cc]) - mean) * rstd * ga + be;
            hi[j] = hv / (1.f + __expf(-hv));
        }
        *(f32x4*)(ob + (size_t)cc * Nn) = lo;
        *(f32x4*)(ob + (size_t)cc * Nn + 4) = hi;
    }
}

// ---------------- launcher ----------------
extern "C" void kernel_launch(void* const* d_in, const int* in_sizes, int n_in,
                              void* d_out, int out_size, void* d_ws, size_t ws_size,
                              hipStream_t stream) {
    (void)in_sizes; (void)n_in; (void)out_size; (void)ws_size;
    const float* x     = (const float*)d_in[0];
    const float* ctx   = (const float*)d_in[1];
    const float* qw    = (const float*)d_in[2];
    const float* qb    = (const float*)d_in[3];
    const float* kw    = (const float*)d_in[4];
    const float* vw    = (const float*)d_in[5];
    const float* ow    = (const float*)d_in[6];
    const float* ob    = (const float*)d_in[7];
    const float* gamma = (const float*)d_in[8];
    const float* beta  = (const float*)d_in[9];
    float* out = (float*)d_out;
    char* ws = (char*)d_ws;

    u16* t    = (u16*)(ws + OFF_T);
    u16* ctxb = (u16*)(ws + OFF_CTXB);
    u16* kqp  = (u16*)(ws + OFF_KQ);
    u16* vop  = (u16*)(ws + OFF_VO);
    float* kqbp = (float*)(ws + OFF_KQB);
    u16* kwb  = (u16*)(ws + OFF_KWB);
    u16* vwb  = (u16*)(ws + OFF_VWB);
    u16* kt   = (u16*)(ws + OFF_KT);
    u16* vc   = (u16*)(ws + OFF_V);
    u16* qwTb = (u16*)(ws + OFF_QWB);
    u16* owb  = (u16*)(ws + OFF_OWB);
    float* gsum = (float*)(ws + OFF_GS);
    float* gsq  = (float*)(ws + OFF_GQ);
    u16* xbt = (u16*)d_out;           // 32MB scratch in out (overwritten by gnapply)

    k_prepall<<<5568, 256, 0, stream>>>(x, xbt, qw, ow, kw, vw, ctx,
                                        qwTb, owb, kwb, vwb, ctxb, gsum);
    k_kv<<<dim3(4, Bn), 256, 0, stream>>>(kwb, vwb, ctxb, kt, vc);
    k_kqvo<<<dim3(8, Bn), 256, 0, stream>>>(kt, qwTb, owb, vc, qb, kqp, kqbp, vop);
    k_fused2<<<dim3(64, Bn), 256, 0, stream>>>(kqp, vop, kqbp, xbt, ob, t, gsum, gsq);
    k_gnapply<<<dim3(64, Bn), 256, 0, stream>>>(t, gsum, gsq, gamma, beta, out);
}

// Round 13
// 120.538 us; speedup vs baseline: 1.3261x; 1.0018x over previous
//
#include <hip/hip_runtime.h>
#include <cstdint>
#include <cstddef>

// ---------------- problem constants ----------------
#define Bn   16
#define Cn   256
#define Nn   4096      // 16^3 spatial
#define Ln   77
#define LPn  80        // padded L rows (scores), 5 tiles of 16
#define LKn  96        // padded L for the collapsed PV/out GEMM K-dim (3 k-steps of 32)
#define CTXn 768
#define Gn   32

typedef unsigned short u16;
typedef unsigned int   u32;
using frag8 = __attribute__((ext_vector_type(8))) short;   // 8 x bf16 (4 VGPR)
using f32x4 = __attribute__((ext_vector_type(4))) float;
using u16x4 = __attribute__((ext_vector_type(4))) u16;
using u16x8 = __attribute__((ext_vector_type(8))) u16;

__device__ __forceinline__ float b2f(u16 b) {
    union { u32 u; float f; } v; v.u = ((u32)b) << 16; return v.f;
}
__device__ __forceinline__ u16 f2b(float f) {  // RNE f32->bf16
    union { float f; u32 u; } v; v.f = f;
    u32 u = v.u;
    return (u16)((u + 0x7fffu + ((u >> 16) & 1u)) >> 16);
}
__device__ __forceinline__ u16x4 cast4(f32x4 s) {
    u16x4 p; p[0] = f2b(s[0]); p[1] = f2b(s[1]); p[2] = f2b(s[2]); p[3] = f2b(s[3]);
    return p;
}
// async global->LDS, 16B per lane. LDS dest must be lane-linear (base + lane*16).
__device__ __forceinline__ void gl16(const u16* g, u16* l) {
    __builtin_amdgcn_global_load_lds((const __attribute__((address_space(1))) u32*)g,
                                     (__attribute__((address_space(3))) u32*)l, 16, 0, 0);
}

// Chunked activation layout (per 64n tile): [kc(32)][row(64)] of 16B chunks (8 ch).
// Chunked weight layout [in-c chunks]: idx = ((k>>3)*256 + r)*8 + (k&7).
// kt chunked:  [b][c-chunk(32)][l(80)][8]  (40KB/b)
// kq chunked:  [b][c-chunk(32)][l(80)][8]  (40KB/b)  kq[l][c] = sum_c' kt[l][c']*qw[c'][c]
// vo chunked:  [b][l-chunk(12)][o(256)][8] (48KB/b)  vo[o][l] = sum_c ow[o][c]*v[c][l]
// vc row-major:[b][l(96)][c(256)]          (48KB/b)
// w  chunked:  [b][nt(64)][l-chunk(12)][n(64)][8] (12KB/tile, 12.6MB total)

// ---------------- ws layout (bytes) ----------------
static const size_t OFF_W    = 0;                   // w, 12,582,912 B
static const size_t OFF_KWB  = 16777216;            // bf16 [256][768] (dead after k_kv)
static const size_t OFF_VWB  = 17170432;            // bf16 [256][768] (dead after k_kv)
static const size_t OFF_CTXB = 31457280;            // bf16 [16][80][768] (dead after k_kv)
static const size_t OFF_KQ   = 31457280;            // overlays dead ctxb (k_kqvo)
static const size_t OFF_VO   = 32112640;
static const size_t OFF_KQB  = 32899072;            // f32 [16][80]
static const size_t OFF_XBT  = 33554432;            // bf16 chunked x [B][64][2048][8], 33.5MB
static const size_t OFF_KT   = 67108864;            // kt chunked
static const size_t OFF_V    = 67764224;            // vc row-major
static const size_t OFF_QWB  = 68550656;            // qwTb chunked
static const size_t OFF_OWB  = 68681728;            // owb chunked

// ---------------- 1: merged prep: x transpose+cast (blocks 0..4095) +
//                    weight/ctx casts (blocks 4096..5567) ----------------
__global__ void k_prepall(const float* __restrict__ x, u16* __restrict__ xbt,
                          const float* __restrict__ qw, const float* __restrict__ ow,
                          const float* __restrict__ kw, const float* __restrict__ vw,
                          const float* __restrict__ ctx,
                          u16* __restrict__ qwTb, u16* __restrict__ owb,
                          u16* __restrict__ kwb, u16* __restrict__ vwb,
                          u16* __restrict__ ctxb) {
    __shared__ float tile[64][65];
    int tid = threadIdx.x;
    if (blockIdx.x < 4096) {
        int blk = blockIdx.x;
        int nt = blk & 63, cq = (blk >> 6) & 3, b = blk >> 8;
        int c0 = cq * 64;
        int tr = tid >> 4, tc4 = (tid & 15) * 4;
#pragma unroll
        for (int i = 0; i < 4; ++i) {
            int cc = tr + i * 16;
            f32x4 vv = *(const f32x4*)(x + ((size_t)(b * Cn + c0 + cc)) * Nn + nt * 64 + tc4);
#pragma unroll
            for (int j = 0; j < 4; ++j) tile[cc][tc4 + j] = vv[j];
        }
        __syncthreads();
        int row = tid & 63, kq_ = tid >> 6;
        u16* xb = xbt + ((size_t)(b * 64 + nt)) * 16384;
#pragma unroll
        for (int it = 0; it < 2; ++it) {
            int kcl = kq_ + it * 4;
            u16x8 pk;
#pragma unroll
            for (int j = 0; j < 8; ++j) pk[j] = f2b(tile[kcl * 8 + j][row]);
            *(u16x8*)(xb + (size_t)(((c0 >> 3) + kcl) * 64 + row) * 8) = pk;
        }
        return;
    }
    int i = (blockIdx.x - 4096) * 256 + tid;       // 376832 total
    if (i < 16384) {
        // qw [c'][c] -> qwTb chunked: idx = ((c'>>3)*256 + c)*8 + (c'&7)
        int e = i * 4; int cp = e >> 8; int c = e & 255;
        f32x4 v4 = *(const f32x4*)(qw + e);
#pragma unroll
        for (int j = 0; j < 4; ++j)
            qwTb[(size_t)((cp >> 3) * 256 + c + j) * 8 + (cp & 7)] = f2b(v4[j]);
    } else if (i < 32768) {
        int e = (i - 16384) * 4; int r = e >> 8; int k = e & 255;
        *(u16x4*)(owb + ((size_t)((k >> 3) * 256 + r) * 8 + (k & 7))) =
            cast4(*(const f32x4*)(ow + e));
    } else if (i < 81920) {
        int j = i - 32768;
        *(u16x4*)(kwb + j * 4) = cast4(*(const f32x4*)(kw + j * 4));
    } else if (i < 131072) {
        int j = i - 81920;
        *(u16x4*)(vwb + j * 4) = cast4(*(const f32x4*)(vw + j * 4));
    } else {
        int j = i - 131072;                        // 0..245759
        int e = j * 4;
        int row = e / CTXn;
        int d = e - row * CTXn;
        int b = row / LPn, l = row - b * LPn;
        u16x4 pk;
        if (l < Ln) {
            pk = cast4(*(const f32x4*)(ctx + ((size_t)(b * Ln + l)) * CTXn + d));
        } else {
            pk[0] = 0; pk[1] = 0; pk[2] = 0; pk[3] = 0;
        }
        *(u16x4*)(ctxb + e) = pk;
    }
}

// ---------------- 2: k/v projections via MFMA (kt chunked, vc row-major) ----------------
__launch_bounds__(256)
__global__ void k_kv(const u16* __restrict__ kwb, const u16* __restrict__ vwb,
                     const u16* __restrict__ ctxb, u16* __restrict__ kt,
                     u16* __restrict__ vc) {
    int b = blockIdx.y;
    int tid = threadIdx.x;
    int wave = tid >> 6, lane = tid & 63;
    int l15 = lane & 15, q4 = lane >> 4;
    int c0 = blockIdx.x * 64 + wave * 16;
    const u16* cb = ctxb + (size_t)b * LPn * CTXn;

    f32x4 ak[5], av[5];
#pragma unroll
    for (int lt = 0; lt < 5; ++lt) {
        ak[lt] = (f32x4){0.f, 0.f, 0.f, 0.f};
        av[lt] = (f32x4){0.f, 0.f, 0.f, 0.f};
    }
    for (int ks = 0; ks < CTXn / 32; ++ks) {
        int kk = ks * 32 + 8 * q4;
        frag8 fk = *(const frag8*)(kwb + (size_t)(c0 + l15) * CTXn + kk);
        frag8 fv = *(const frag8*)(vwb + (size_t)(c0 + l15) * CTXn + kk);
#pragma unroll
        for (int lt = 0; lt < 5; ++lt) {
            frag8 fc = *(const frag8*)(cb + (size_t)(lt * 16 + l15) * CTXn + kk);
            ak[lt] = __builtin_amdgcn_mfma_f32_16x16x32_bf16(fk, fc, ak[lt], 0, 0, 0);
            av[lt] = __builtin_amdgcn_mfma_f32_16x16x32_bf16(fc, fv, av[lt], 0, 0, 0);
        }
    }
    int cc0 = c0 + q4 * 4;
    u16* ktb = kt + (size_t)b * 20480;
    u16* vcb = vc + (size_t)b * 24576;
#pragma unroll
    for (int lt = 0; lt < 5; ++lt) {
        *(u16x4*)(ktb + (size_t)((cc0 >> 3) * LPn + lt * 16 + l15) * 8 + (cc0 & 7)) = cast4(ak[lt]);
#pragma unroll
        for (int r = 0; r < 4; ++r)
            vcb[(size_t)(lt * 16 + q4 * 4 + r) * 256 + c0 + l15] = f2b(av[lt][r]);
    }
    int cb0 = blockIdx.x * 64;
    for (int idx = tid; idx < 16 * 64; idx += 256)
        vcb[(size_t)(80 + (idx >> 6)) * 256 + cb0 + (idx & 63)] = 0;
}

// ---------------- 3: kq / kqb / vo precompute ----------------
__launch_bounds__(256)
__global__ void k_kqvo(const u16* __restrict__ kt, const u16* __restrict__ qwTb,
                       const u16* __restrict__ owb, const u16* __restrict__ vc,
                       const float* __restrict__ qb, u16* __restrict__ kq,
                       float* __restrict__ kqb, u16* __restrict__ vo) {
    int bx = blockIdx.x, b = blockIdx.y;
    int tid = threadIdx.x;
    int w = tid >> 6, lane = tid & 63;
    int l15 = lane & 15, q4 = lane >> 4;
    const u16* ktb = kt + (size_t)b * 20480;

    if (bx < 4) {
        int c = bx * 64 + w * 16 + l15;
        f32x4 acc[5];
#pragma unroll
        for (int lt = 0; lt < 5; ++lt) acc[lt] = (f32x4){0.f, 0.f, 0.f, 0.f};
#pragma unroll
        for (int ks = 0; ks < 8; ++ks) {
            frag8 bqw = *(const frag8*)(qwTb + (size_t)((ks * 4 + q4) * 256 + c) * 8);
#pragma unroll
            for (int lt = 0; lt < 5; ++lt) {
                frag8 akt = *(const frag8*)(ktb + (size_t)((ks * 4 + q4) * 80 + lt * 16 + l15) * 8);
                acc[lt] = __builtin_amdgcn_mfma_f32_16x16x32_bf16(akt, bqw, acc[lt], 0, 0, 0);
            }
        }
        u16* kqB = kq + (size_t)b * 20480;
#pragma unroll
        for (int lt = 0; lt < 5; ++lt)
#pragma unroll
            for (int r = 0; r < 4; ++r) {
                int l = lt * 16 + q4 * 4 + r;
                kqB[(size_t)((c >> 3) * 80 + l) * 8 + (c & 7)] = f2b(acc[lt][r]);
            }
        if (bx == 0 && tid < 80) {
            float s = 0.f;
            for (int kc = 0; kc < 32; ++kc) {
                u16x8 kv8 = *(const u16x8*)(ktb + (size_t)(kc * 80 + tid) * 8);
#pragma unroll
                for (int j = 0; j < 8; ++j) s += b2f(kv8[j]) * qb[kc * 8 + j];
            }
            kqb[b * 80 + tid] = s;
        }
    } else {
        int ob = (bx - 4) * 64 + w * 16;
        const u16* vcb = vc + (size_t)b * 24576;
        f32x4 acc[6];
#pragma unroll
        for (int lt = 0; lt < 6; ++lt) acc[lt] = (f32x4){0.f, 0.f, 0.f, 0.f};
#pragma unroll
        for (int ks = 0; ks < 8; ++ks) {
            frag8 aow = *(const frag8*)(owb + (size_t)((ks * 4 + q4) * 256 + ob + l15) * 8);
#pragma unroll
            for (int lt = 0; lt < 6; ++lt) {
                frag8 bvc = *(const frag8*)(vcb + (size_t)(lt * 16 + l15) * 256 + ks * 32 + q4 * 8);
                acc[lt] = __builtin_amdgcn_mfma_f32_16x16x32_bf16(aow, bvc, acc[lt], 0, 0, 0);
            }
        }
        u16* voB = vo + (size_t)b * 24576;
#pragma unroll
        for (int lt = 0; lt < 6; ++lt) {
            int l = lt * 16 + l15;
#pragma unroll
            for (int r = 0; r < 4; ++r) {
                int o = ob + q4 * 4 + r;
                voB[(size_t)((l >> 3) * 256 + o) * 8 + (l & 7)] = f2b(acc[lt][r]);
            }
        }
    }
}

// ---------------- 4: scores + softmax -> w (global) ----------------
// One 64n tile per block, 4 waves, 1 barrier. kq staged via async gl16 burst.
__launch_bounds__(256)
__global__ void k_score(const u16* __restrict__ kq, const float* __restrict__ kqb,
                        const u16* __restrict__ xbt, u16* __restrict__ wg) {
    int nt = blockIdx.x, b = blockIdx.y;
    int tid = threadIdx.x;
    int w = tid >> 6, lane = tid & 63;
    int l15 = lane & 15, q4 = lane >> 4;
    int rw = w * 16;

    __shared__ __align__(16) u16 skq[20480];        // 40KB kq (chunked [kc][l])

    const u16* kqB = kq + (size_t)b * 20480;
#pragma unroll
    for (int j = 0; j < 10; ++j) {
        int c = j * 256 + tid;
        gl16(kqB + (size_t)c * 8, &skq[(size_t)c * 8]);
    }
    // preload this wave's x frags while kq is in flight
    const u16* xb = xbt + ((size_t)(b * 64 + nt)) * 16384;
    frag8 bq[8];
#pragma unroll
    for (int ks = 0; ks < 8; ++ks)
        bq[ks] = *(const frag8*)(xb + (size_t)((ks * 4 + q4) * 64 + rw + l15) * 8);
    __syncthreads();

    f32x4 s5[5];
#pragma unroll
    for (int lt = 0; lt < 5; ++lt) s5[lt] = (f32x4){0.f, 0.f, 0.f, 0.f};
#pragma unroll
    for (int ks = 0; ks < 8; ++ks)
#pragma unroll
        for (int lt = 0; lt < 5; ++lt) {
            frag8 akq = *(const frag8*)&skq[(size_t)((ks * 4 + q4) * 80 + lt * 16 + l15) * 8];
            s5[lt] = __builtin_amdgcn_mfma_f32_16x16x32_bf16(akq, bq[ks], s5[lt], 0, 0, 0);
        }
    const float* kqbB = kqb + b * 80;
#pragma unroll
    for (int lt = 0; lt < 5; ++lt) {
        f32x4 bb = *(const f32x4*)(kqbB + lt * 16 + q4 * 4);
        s5[lt] += bb;
    }
    // softmax over l; lane: n = l15 (rows rw..), l = lt*16 + q4*4 + r
    float m = -3e38f;
#pragma unroll
    for (int lt = 0; lt < 5; ++lt)
#pragma unroll
        for (int r = 0; r < 4; ++r) {
            int l = lt * 16 + q4 * 4 + r;
            if (l < Ln) m = fmaxf(m, s5[lt][r]);
        }
    m = fmaxf(m, __shfl_xor(m, 16));
    m = fmaxf(m, __shfl_xor(m, 32));
    float p[5][4];
    float sum = 0.f;
#pragma unroll
    for (int lt = 0; lt < 5; ++lt)
#pragma unroll
        for (int r = 0; r < 4; ++r) {
            int l = lt * 16 + q4 * 4 + r;
            float e = (l < Ln) ? __expf(s5[lt][r] - m) : 0.f;
            p[lt][r] = e;
            sum += e;
        }
    sum += __shfl_xor(sum, 16);
    sum += __shfl_xor(sum, 32);
    float inv = 1.f / sum;

    // store w chunked to global; zero-pad chunks 10,11 for this wave's rows
    u16* wt = wg + ((size_t)(b * 64 + nt)) * 6144;
#pragma unroll
    for (int lt = 0; lt < 5; ++lt) {
        int l4 = lt * 16 + q4 * 4;
        u16x4 pk;
#pragma unroll
        for (int r = 0; r < 4; ++r) pk[r] = f2b(p[lt][r] * inv);
        *(u16x4*)(wt + (size_t)((l4 >> 3) * 64 + rw + l15) * 8 + (l4 & 7)) = pk;
    }
    u16x4 z; z[0] = 0; z[1] = 0; z[2] = 0; z[3] = 0;
    *(u16x4*)(wt + (size_t)((10 + (lane >> 5)) * 64 + rw + ((lane >> 1) & 15)) * 8 + (lane & 1) * 4) = z;
}

// ---------------- 5: t-GEMM + residual + block-local GroupNorm + Swish -> out ----------------
// Block = (16-channel slice, b) = 2 whole GN groups; 8 waves; wave w does n-tiles w,w+8,..
// Pass A: stats (recompute-cheap). LDS-reduce. Pass B: recompute, normalize, write f32 out.
__launch_bounds__(512)
__global__ void k_pass2(const u16* __restrict__ wg, const u16* __restrict__ vo,
                        const u16* __restrict__ xbt, const float* __restrict__ obias,
                        const float* __restrict__ gamma, const float* __restrict__ beta,
                        float* __restrict__ out) {
    int bx = blockIdx.x, b = blockIdx.y;
    int tid = threadIdx.x;
    int w = tid >> 6, lane = tid & 63;
    int l15 = lane & 15, q4 = lane >> 4;
    int o0 = bx * 16;
    int o4 = o0 + q4 * 4;

    __shared__ float sp[8][2], sq[8][2];

    const u16* voB = vo + (size_t)b * 24576;
    frag8 af[3];
#pragma unroll
    for (int ks = 0; ks < 3; ++ks)
        af[ks] = *(const frag8*)(voB + (size_t)((ks * 4 + q4) * 256 + o0 + l15) * 8);
    f32x4 ob4 = *(const f32x4*)(obias + o4);
    size_t kcb = (size_t)(o4 >> 3) * 64;
    int off = o4 & 7;

    float gps = 0.f, gpq = 0.f;
    // ---- pass A: stats ----
    for (int i = 0; i < 8; ++i) {
        int T = w + i * 8;
        const u16* wt = wg + ((size_t)(b * 64 + T)) * 6144;
        const u16* xt = xbt + ((size_t)(b * 64 + T)) * 16384;
        f32x4 dcc[4];
#pragma unroll
        for (int n4 = 0; n4 < 4; ++n4) dcc[n4] = (f32x4){0.f, 0.f, 0.f, 0.f};
#pragma unroll
        for (int ks = 0; ks < 3; ++ks)
#pragma unroll
            for (int n4 = 0; n4 < 4; ++n4) {
                frag8 wf = *(const frag8*)(wt + (size_t)((ks * 4 + q4) * 64 + n4 * 16 + l15) * 8);
                dcc[n4] = __builtin_amdgcn_mfma_f32_16x16x32_bf16(af[ks], wf, dcc[n4], 0, 0, 0);
            }
#pragma unroll
        for (int n4 = 0; n4 < 4; ++n4) {
            u16x4 xv = *(const u16x4*)(xt + (kcb + n4 * 16 + l15) * 8 + off);
#pragma unroll
            for (int r = 0; r < 4; ++r) {
                float val = dcc[n4][r] + ob4[r] + b2f(xv[r]);
                gps += val; gpq += val * val;
            }
        }
    }
    // reduce within 32-lane halves (each half = one GN group)
    gps += __shfl_xor(gps, 1);  gpq += __shfl_xor(gpq, 1);
    gps += __shfl_xor(gps, 2);  gpq += __shfl_xor(gpq, 2);
    gps += __shfl_xor(gps, 4);  gpq += __shfl_xor(gpq, 4);
    gps += __shfl_xor(gps, 8);  gpq += __shfl_xor(gpq, 8);
    gps += __shfl_xor(gps, 16); gpq += __shfl_xor(gpq, 16);
    if ((lane & 31) == 0) { sp[w][lane >> 5] = gps; sq[w][lane >> 5] = gpq; }
    __syncthreads();
    int gh = q4 >> 1;
    float S = 0.f, Q = 0.f;
#pragma unroll
    for (int j = 0; j < 8; ++j) { S += sp[j][gh]; Q += sq[j][gh]; }
    float mean = S * (1.0f / 32768.f);
    float var = Q * (1.0f / 32768.f) - mean * mean;
    float rstd = rsqrtf(var + 1e-5f);
    f32x4 ga4 = *(const f32x4*)(gamma + o4);
    f32x4 be4 = *(const f32x4*)(beta + o4);

    // ---- pass B: recompute, normalize + swish, write f32 out ----
    for (int i = 0; i < 8; ++i) {
        int T = w + i * 8;
        const u16* wt = wg + ((size_t)(b * 64 + T)) * 6144;
        const u16* xt = xbt + ((size_t)(b * 64 + T)) * 16384;
        f32x4 dcc[4];
#pragma unroll
        for (int n4 = 0; n4 < 4; ++n4) dcc[n4] = (f32x4){0.f, 0.f, 0.f, 0.f};
#pragma unroll
        for (int ks = 0; ks < 3; ++ks)
#pragma unroll
            for (int n4 = 0; n4 < 4; ++n4) {
                frag8 wf = *(const frag8*)(wt + (size_t)((ks * 4 + q4) * 64 + n4 * 16 + l15) * 8);
                dcc[n4] = __builtin_amdgcn_mfma_f32_16x16x32_bf16(af[ks], wf, dcc[n4], 0, 0, 0);
            }
        float* ob = out + ((size_t)(b * Cn + o4)) * Nn + T * 64;
#pragma unroll
        for (int n4 = 0; n4 < 4; ++n4) {
            u16x4 xv = *(const u16x4*)(xt + (kcb + n4 * 16 + l15) * 8 + off);
#pragma unroll
            for (int r = 0; r < 4; ++r) {
                float val = dcc[n4][r] + ob4[r] + b2f(xv[r]);
                float hv = (val - mean) * rstd * ga4[r] + be4[r];
                ob[(size_t)r * Nn + n4 * 16 + l15] = hv / (1.f + __expf(-hv));
            }
        }
    }
}

// ---------------- launcher ----------------
extern "C" void kernel_launch(void* const* d_in, const int* in_sizes, int n_in,
                              void* d_out, int out_size, void* d_ws, size_t ws_size,
                              hipStream_t stream) {
    (void)in_sizes; (void)n_in; (void)out_size; (void)ws_size;
    const float* x     = (const float*)d_in[0];
    const float* ctx   = (const float*)d_in[1];
    const float* qw    = (const float*)d_in[2];
    const float* qb    = (const float*)d_in[3];
    const float* kw    = (const float*)d_in[4];
    const float* vw    = (const float*)d_in[5];
    const float* ow    = (const float*)d_in[6];
    const float* ob    = (const float*)d_in[7];
    const float* gamma = (const float*)d_in[8];
    const float* beta  = (const float*)d_in[9];
    float* out = (float*)d_out;
    char* ws = (char*)d_ws;

    u16* wg   = (u16*)(ws + OFF_W);
    u16* kwb  = (u16*)(ws + OFF_KWB);
    u16* vwb  = (u16*)(ws + OFF_VWB);
    u16* ctxb = (u16*)(ws + OFF_CTXB);
    u16* kqp  = (u16*)(ws + OFF_KQ);
    u16* vop  = (u16*)(ws + OFF_VO);
    float* kqbp = (float*)(ws + OFF_KQB);
    u16* xbt  = (u16*)(ws + OFF_XBT);
    u16* kt   = (u16*)(ws + OFF_KT);
    u16* vc   = (u16*)(ws + OFF_V);
    u16* qwTb = (u16*)(ws + OFF_QWB);
    u16* owb  = (u16*)(ws + OFF_OWB);

    k_prepall<<<5568, 256, 0, stream>>>(x, xbt, qw, ow, kw, vw, ctx,
                                        qwTb, owb, kwb, vwb, ctxb);
    k_kv<<<dim3(4, Bn), 256, 0, stream>>>(kwb, vwb, ctxb, kt, vc);
    k_kqvo<<<dim3(8, Bn), 256, 0, stream>>>(kt, qwTb, owb, vc, qb, kqp, kqbp, vop);
    k_score<<<dim3(64, Bn), 256, 0, stream>>>(kqp, kqbp, xbt, wg);
    k_pass2<<<dim3(16, Bn), 512, 0, stream>>>(wg, vop, xbt, ob, gamma, beta, out);
}

// Round 14
// 103.031 us; speedup vs baseline: 1.5514x; 1.1699x over previous
//
#include <hip/hip_runtime.h>
#include <cstdint>
#include <cstddef>

// ---------------- problem constants ----------------
#define Bn   16
#define Cn   256
#define Nn   4096      // 16^3 spatial
#define Ln   77
#define LPn  80        // padded L rows (scores), 5 tiles of 16
#define LKn  96        // padded L for the collapsed PV/out GEMM K-dim (3 k-steps of 32)
#define CTXn 768
#define Gn   32

typedef unsigned short u16;
typedef unsigned int   u32;
using frag8 = __attribute__((ext_vector_type(8))) short;   // 8 x bf16 (4 VGPR)
using f32x4 = __attribute__((ext_vector_type(4))) float;
using u16x4 = __attribute__((ext_vector_type(4))) u16;
using u16x8 = __attribute__((ext_vector_type(8))) u16;

__device__ __forceinline__ float b2f(u16 b) {
    union { u32 u; float f; } v; v.u = ((u32)b) << 16; return v.f;
}
__device__ __forceinline__ u16 f2b(float f) {  // RNE f32->bf16
    union { float f; u32 u; } v; v.f = f;
    u32 u = v.u;
    return (u16)((u + 0x7fffu + ((u >> 16) & 1u)) >> 16);
}
__device__ __forceinline__ u16x4 cast4(f32x4 s) {
    u16x4 p; p[0] = f2b(s[0]); p[1] = f2b(s[1]); p[2] = f2b(s[2]); p[3] = f2b(s[3]);
    return p;
}
// async global->LDS, 16B per lane. LDS dest must be lane-linear (base + lane*16).
__device__ __forceinline__ void gl16(const u16* g, u16* l) {
    __builtin_amdgcn_global_load_lds((const __attribute__((address_space(1))) u32*)g,
                                     (__attribute__((address_space(3))) u32*)l, 16, 0, 0);
}

// Chunked activation layout (per 64n tile): [kc(32)][row(64)] of 16B chunks (8 ch).
// Chunked weight layout [in-c chunks]: idx = ((k>>3)*256 + r)*8 + (k&7).
// kt chunked:  [b][c-chunk(32)][l(80)][8]  (40KB/b)
// kq chunked:  [b][c-chunk(32)][l(80)][8]  (40KB/b)  kq[l][c] = sum_c' kt[l][c']*qw[c'][c]
// vo chunked:  [b][l-chunk(12)][o(256)][8] (48KB/b)  vo[o][l] = sum_c ow[o][c]*v[c][l]
// vc row-major:[b][l(96)][c(256)]          (48KB/b)
// w  chunked:  [b][nt(64)][l-chunk(12)][n(64)][8] (12KB/tile, 12.6MB total)

// ---------------- ws layout (bytes) ----------------
static const size_t OFF_W    = 0;                   // w, 12,582,912 B
static const size_t OFF_KWB  = 16777216;            // bf16 [256][768] (dead after k_kv)
static const size_t OFF_VWB  = 17170432;            // bf16 [256][768] (dead after k_kv)
static const size_t OFF_CTXB = 31457280;            // bf16 [16][80][768] (dead after k_kv)
static const size_t OFF_KQ   = 31457280;            // overlays dead ctxb (k_kqvo)
static const size_t OFF_VO   = 32112640;
static const size_t OFF_KQB  = 32899072;            // f32 [16][80]
static const size_t OFF_XBT  = 33554432;            // bf16 chunked x [B][64][2048][8], 33.5MB
static const size_t OFF_KT   = 67108864;            // kt chunked
static const size_t OFF_V    = 67764224;            // vc row-major
static const size_t OFF_QWB  = 68550656;            // qwTb chunked
static const size_t OFF_OWB  = 68681728;            // owb chunked

// ---------------- 1: merged prep: x transpose+cast (blocks 0..4095) +
//                    weight/ctx casts (blocks 4096..5567) ----------------
__global__ void k_prepall(const float* __restrict__ x, u16* __restrict__ xbt,
                          const float* __restrict__ qw, const float* __restrict__ ow,
                          const float* __restrict__ kw, const float* __restrict__ vw,
                          const float* __restrict__ ctx,
                          u16* __restrict__ qwTb, u16* __restrict__ owb,
                          u16* __restrict__ kwb, u16* __restrict__ vwb,
                          u16* __restrict__ ctxb) {
    __shared__ float tile[64][65];
    int tid = threadIdx.x;
    if (blockIdx.x < 4096) {
        int blk = blockIdx.x;
        int nt = blk & 63, cq = (blk >> 6) & 3, b = blk >> 8;
        int c0 = cq * 64;
        int tr = tid >> 4, tc4 = (tid & 15) * 4;
#pragma unroll
        for (int i = 0; i < 4; ++i) {
            int cc = tr + i * 16;
            f32x4 vv = *(const f32x4*)(x + ((size_t)(b * Cn + c0 + cc)) * Nn + nt * 64 + tc4);
#pragma unroll
            for (int j = 0; j < 4; ++j) tile[cc][tc4 + j] = vv[j];
        }
        __syncthreads();
        int row = tid & 63, kq_ = tid >> 6;
        u16* xb = xbt + ((size_t)(b * 64 + nt)) * 16384;
#pragma unroll
        for (int it = 0; it < 2; ++it) {
            int kcl = kq_ + it * 4;
            u16x8 pk;
#pragma unroll
            for (int j = 0; j < 8; ++j) pk[j] = f2b(tile[kcl * 8 + j][row]);
            *(u16x8*)(xb + (size_t)(((c0 >> 3) + kcl) * 64 + row) * 8) = pk;
        }
        return;
    }
    int i = (blockIdx.x - 4096) * 256 + tid;       // 376832 total
    if (i < 16384) {
        // qw [c'][c] -> qwTb chunked: idx = ((c'>>3)*256 + c)*8 + (c'&7)
        int e = i * 4; int cp = e >> 8; int c = e & 255;
        f32x4 v4 = *(const f32x4*)(qw + e);
#pragma unroll
        for (int j = 0; j < 4; ++j)
            qwTb[(size_t)((cp >> 3) * 256 + c + j) * 8 + (cp & 7)] = f2b(v4[j]);
    } else if (i < 32768) {
        int e = (i - 16384) * 4; int r = e >> 8; int k = e & 255;
        *(u16x4*)(owb + ((size_t)((k >> 3) * 256 + r) * 8 + (k & 7))) =
            cast4(*(const f32x4*)(ow + e));
    } else if (i < 81920) {
        int j = i - 32768;
        *(u16x4*)(kwb + j * 4) = cast4(*(const f32x4*)(kw + j * 4));
    } else if (i < 131072) {
        int j = i - 81920;
        *(u16x4*)(vwb + j * 4) = cast4(*(const f32x4*)(vw + j * 4));
    } else {
        int j = i - 131072;                        // 0..245759
        int e = j * 4;
        int row = e / CTXn;
        int d = e - row * CTXn;
        int b = row / LPn, l = row - b * LPn;
        u16x4 pk;
        if (l < Ln) {
            pk = cast4(*(const f32x4*)(ctx + ((size_t)(b * Ln + l)) * CTXn + d));
        } else {
            pk[0] = 0; pk[1] = 0; pk[2] = 0; pk[3] = 0;
        }
        *(u16x4*)(ctxb + e) = pk;
    }
}

// ---------------- 2: k/v projections via MFMA (kt chunked, vc row-major) ----------------
__launch_bounds__(256)
__global__ void k_kv(const u16* __restrict__ kwb, const u16* __restrict__ vwb,
                     const u16* __restrict__ ctxb, u16* __restrict__ kt,
                     u16* __restrict__ vc) {
    int b = blockIdx.y;
    int tid = threadIdx.x;
    int wave = tid >> 6, lane = tid & 63;
    int l15 = lane & 15, q4 = lane >> 4;
    int c0 = blockIdx.x * 64 + wave * 16;
    const u16* cb = ctxb + (size_t)b * LPn * CTXn;

    f32x4 ak[5], av[5];
#pragma unroll
    for (int lt = 0; lt < 5; ++lt) {
        ak[lt] = (f32x4){0.f, 0.f, 0.f, 0.f};
        av[lt] = (f32x4){0.f, 0.f, 0.f, 0.f};
    }
    for (int ks = 0; ks < CTXn / 32; ++ks) {
        int kk = ks * 32 + 8 * q4;
        frag8 fk = *(const frag8*)(kwb + (size_t)(c0 + l15) * CTXn + kk);
        frag8 fv = *(const frag8*)(vwb + (size_t)(c0 + l15) * CTXn + kk);
#pragma unroll
        for (int lt = 0; lt < 5; ++lt) {
            frag8 fc = *(const frag8*)(cb + (size_t)(lt * 16 + l15) * CTXn + kk);
            ak[lt] = __builtin_amdgcn_mfma_f32_16x16x32_bf16(fk, fc, ak[lt], 0, 0, 0);
            av[lt] = __builtin_amdgcn_mfma_f32_16x16x32_bf16(fc, fv, av[lt], 0, 0, 0);
        }
    }
    int cc0 = c0 + q4 * 4;
    u16* ktb = kt + (size_t)b * 20480;
    u16* vcb = vc + (size_t)b * 24576;
#pragma unroll
    for (int lt = 0; lt < 5; ++lt) {
        *(u16x4*)(ktb + (size_t)((cc0 >> 3) * LPn + lt * 16 + l15) * 8 + (cc0 & 7)) = cast4(ak[lt]);
#pragma unroll
        for (int r = 0; r < 4; ++r)
            vcb[(size_t)(lt * 16 + q4 * 4 + r) * 256 + c0 + l15] = f2b(av[lt][r]);
    }
    int cb0 = blockIdx.x * 64;
    for (int idx = tid; idx < 16 * 64; idx += 256)
        vcb[(size_t)(80 + (idx >> 6)) * 256 + cb0 + (idx & 63)] = 0;
}

// ---------------- 3: kq / kqb / vo precompute ----------------
__launch_bounds__(256)
__global__ void k_kqvo(const u16* __restrict__ kt, const u16* __restrict__ qwTb,
                       const u16* __restrict__ owb, const u16* __restrict__ vc,
                       const float* __restrict__ qb, u16* __restrict__ kq,
                       float* __restrict__ kqb, u16* __restrict__ vo) {
    int bx = blockIdx.x, b = blockIdx.y;
    int tid = threadIdx.x;
    int w = tid >> 6, lane = tid & 63;
    int l15 = lane & 15, q4 = lane >> 4;
    const u16* ktb = kt + (size_t)b * 20480;

    if (bx < 4) {
        int c = bx * 64 + w * 16 + l15;
        f32x4 acc[5];
#pragma unroll
        for (int lt = 0; lt < 5; ++lt) acc[lt] = (f32x4){0.f, 0.f, 0.f, 0.f};
#pragma unroll
        for (int ks = 0; ks < 8; ++ks) {
            frag8 bqw = *(const frag8*)(qwTb + (size_t)((ks * 4 + q4) * 256 + c) * 8);
#pragma unroll
            for (int lt = 0; lt < 5; ++lt) {
                frag8 akt = *(const frag8*)(ktb + (size_t)((ks * 4 + q4) * 80 + lt * 16 + l15) * 8);
                acc[lt] = __builtin_amdgcn_mfma_f32_16x16x32_bf16(akt, bqw, acc[lt], 0, 0, 0);
            }
        }
        u16* kqB = kq + (size_t)b * 20480;
#pragma unroll
        for (int lt = 0; lt < 5; ++lt)
#pragma unroll
            for (int r = 0; r < 4; ++r) {
                int l = lt * 16 + q4 * 4 + r;
                kqB[(size_t)((c >> 3) * 80 + l) * 8 + (c & 7)] = f2b(acc[lt][r]);
            }
        if (bx == 0 && tid < 80) {
            float s = 0.f;
            for (int kc = 0; kc < 32; ++kc) {
                u16x8 kv8 = *(const u16x8*)(ktb + (size_t)(kc * 80 + tid) * 8);
#pragma unroll
                for (int j = 0; j < 8; ++j) s += b2f(kv8[j]) * qb[kc * 8 + j];
            }
            kqb[b * 80 + tid] = s;
        }
    } else {
        int ob = (bx - 4) * 64 + w * 16;
        const u16* vcb = vc + (size_t)b * 24576;
        f32x4 acc[6];
#pragma unroll
        for (int lt = 0; lt < 6; ++lt) acc[lt] = (f32x4){0.f, 0.f, 0.f, 0.f};
#pragma unroll
        for (int ks = 0; ks < 8; ++ks) {
            frag8 aow = *(const frag8*)(owb + (size_t)((ks * 4 + q4) * 256 + ob + l15) * 8);
#pragma unroll
            for (int lt = 0; lt < 6; ++lt) {
                frag8 bvc = *(const frag8*)(vcb + (size_t)(lt * 16 + l15) * 256 + ks * 32 + q4 * 8);
                acc[lt] = __builtin_amdgcn_mfma_f32_16x16x32_bf16(aow, bvc, acc[lt], 0, 0, 0);
            }
        }
        u16* voB = vo + (size_t)b * 24576;
#pragma unroll
        for (int lt = 0; lt < 6; ++lt) {
            int l = lt * 16 + l15;
#pragma unroll
            for (int r = 0; r < 4; ++r) {
                int o = ob + q4 * 4 + r;
                voB[(size_t)((l >> 3) * 256 + o) * 8 + (l & 7)] = f2b(acc[lt][r]);
            }
        }
    }
}

// ---------------- 4: scores + softmax -> w (global) ----------------
// One 64n tile per block, 4 waves, 1 barrier. kq staged via async gl16 burst.
__launch_bounds__(256)
__global__ void k_score(const u16* __restrict__ kq, const float* __restrict__ kqb,
                        const u16* __restrict__ xbt, u16* __restrict__ wg) {
    int nt = blockIdx.x, b = blockIdx.y;
    int tid = threadIdx.x;
    int w = tid >> 6, lane = tid & 63;
    int l15 = lane & 15, q4 = lane >> 4;
    int rw = w * 16;

    __shared__ __align__(16) u16 skq[20480];        // 40KB kq (chunked [kc][l])

    const u16* kqB = kq + (size_t)b * 20480;
#pragma unroll
    for (int j = 0; j < 10; ++j) {
        int c = j * 256 + tid;
        gl16(kqB + (size_t)c * 8, &skq[(size_t)c * 8]);
    }
    // preload this wave's x frags while kq is in flight
    const u16* xb = xbt + ((size_t)(b * 64 + nt)) * 16384;
    frag8 bq[8];
#pragma unroll
    for (int ks = 0; ks < 8; ++ks)
        bq[ks] = *(const frag8*)(xb + (size_t)((ks * 4 + q4) * 64 + rw + l15) * 8);
    __syncthreads();

    f32x4 s5[5];
#pragma unroll
    for (int lt = 0; lt < 5; ++lt) s5[lt] = (f32x4){0.f, 0.f, 0.f, 0.f};
#pragma unroll
    for (int ks = 0; ks < 8; ++ks)
#pragma unroll
        for (int lt = 0; lt < 5; ++lt) {
            frag8 akq = *(const frag8*)&skq[(size_t)((ks * 4 + q4) * 80 + lt * 16 + l15) * 8];
            s5[lt] = __builtin_amdgcn_mfma_f32_16x16x32_bf16(akq, bq[ks], s5[lt], 0, 0, 0);
        }
    const float* kqbB = kqb + b * 80;
#pragma unroll
    for (int lt = 0; lt < 5; ++lt) {
        f32x4 bb = *(const f32x4*)(kqbB + lt * 16 + q4 * 4);
        s5[lt] += bb;
    }
    // softmax over l; lane: n = l15 (rows rw..), l = lt*16 + q4*4 + r
    float m = -3e38f;
#pragma unroll
    for (int lt = 0; lt < 5; ++lt)
#pragma unroll
        for (int r = 0; r < 4; ++r) {
            int l = lt * 16 + q4 * 4 + r;
            if (l < Ln) m = fmaxf(m, s5[lt][r]);
        }
    m = fmaxf(m, __shfl_xor(m, 16));
    m = fmaxf(m, __shfl_xor(m, 32));
    float p[5][4];
    float sum = 0.f;
#pragma unroll
    for (int lt = 0; lt < 5; ++lt)
#pragma unroll
        for (int r = 0; r < 4; ++r) {
            int l = lt * 16 + q4 * 4 + r;
            float e = (l < Ln) ? __expf(s5[lt][r] - m) : 0.f;
            p[lt][r] = e;
            sum += e;
        }
    sum += __shfl_xor(sum, 16);
    sum += __shfl_xor(sum, 32);
    float inv = 1.f / sum;

    // store w chunked to global; zero-pad chunks 10,11 for this wave's rows
    u16* wt = wg + ((size_t)(b * 64 + nt)) * 6144;
#pragma unroll
    for (int lt = 0; lt < 5; ++lt) {
        int l4 = lt * 16 + q4 * 4;
        u16x4 pk;
#pragma unroll
        for (int r = 0; r < 4; ++r) pk[r] = f2b(p[lt][r] * inv);
        *(u16x4*)(wt + (size_t)((l4 >> 3) * 64 + rw + l15) * 8 + (l4 & 7)) = pk;
    }
    u16x4 z; z[0] = 0; z[1] = 0; z[2] = 0; z[3] = 0;
    *(u16x4*)(wt + (size_t)((10 + (lane >> 5)) * 64 + rw + ((lane >> 1) & 15)) * 8 + (lane & 1) * 4) = z;
}

// ---------------- 5: t-GEMM + residual + block-local GroupNorm + Swish -> out ----------------
// Block = (16-channel slice, b) = 2 whole GN groups; 8 waves; wave w does n-tiles w,w+8,..
// SINGLE compute pass: t held in 128 VGPRs across the stats reduction; then
// normalize from registers and write f32 out. No recompute, no second w/xbt read.
__launch_bounds__(512, 2)
__global__ void k_pass2(const u16* __restrict__ wg, const u16* __restrict__ vo,
                        const u16* __restrict__ xbt, const float* __restrict__ obias,
                        const float* __restrict__ gamma, const float* __restrict__ beta,
                        float* __restrict__ out) {
    int bx = blockIdx.x, b = blockIdx.y;
    int tid = threadIdx.x;
    int w = tid >> 6, lane = tid & 63;
    int l15 = lane & 15, q4 = lane >> 4;
    int o0 = bx * 16;
    int o4 = o0 + q4 * 4;

    __shared__ float sp[8][2], sq[8][2];

    const u16* voB = vo + (size_t)b * 24576;
    frag8 af[3];
#pragma unroll
    for (int ks = 0; ks < 3; ++ks)
        af[ks] = *(const frag8*)(voB + (size_t)((ks * 4 + q4) * 256 + o0 + l15) * 8);
    f32x4 ob4 = *(const f32x4*)(obias + o4);
    size_t kcb = (size_t)(o4 >> 3) * 64;
    int off = o4 & 7;

    // ---- single compute pass: t into registers + stats ----
    f32x4 tv[8][4];                                 // 128 f32 / thread
    float gps = 0.f, gpq = 0.f;
#pragma unroll
    for (int i = 0; i < 8; ++i) {
        int T = w + i * 8;
        const u16* wt = wg + ((size_t)(b * 64 + T)) * 6144;
        const u16* xt = xbt + ((size_t)(b * 64 + T)) * 16384;
#pragma unroll
        for (int n4 = 0; n4 < 4; ++n4) tv[i][n4] = (f32x4){0.f, 0.f, 0.f, 0.f};
#pragma unroll
        for (int ks = 0; ks < 3; ++ks)
#pragma unroll
            for (int n4 = 0; n4 < 4; ++n4) {
                frag8 wf = *(const frag8*)(wt + (size_t)((ks * 4 + q4) * 64 + n4 * 16 + l15) * 8);
                tv[i][n4] = __builtin_amdgcn_mfma_f32_16x16x32_bf16(af[ks], wf, tv[i][n4], 0, 0, 0);
            }
#pragma unroll
        for (int n4 = 0; n4 < 4; ++n4) {
            u16x4 xv = *(const u16x4*)(xt + (kcb + n4 * 16 + l15) * 8 + off);
#pragma unroll
            for (int r = 0; r < 4; ++r) {
                float val = tv[i][n4][r] + ob4[r] + b2f(xv[r]);
                tv[i][n4][r] = val;
                gps += val; gpq += val * val;
            }
        }
    }
    // reduce within 32-lane halves (each half = one GN group)
    gps += __shfl_xor(gps, 1);  gpq += __shfl_xor(gpq, 1);
    gps += __shfl_xor(gps, 2);  gpq += __shfl_xor(gpq, 2);
    gps += __shfl_xor(gps, 4);  gpq += __shfl_xor(gpq, 4);
    gps += __shfl_xor(gps, 8);  gpq += __shfl_xor(gpq, 8);
    gps += __shfl_xor(gps, 16); gpq += __shfl_xor(gpq, 16);
    if ((lane & 31) == 0) { sp[w][lane >> 5] = gps; sq[w][lane >> 5] = gpq; }
    __syncthreads();
    int gh = q4 >> 1;
    float S = 0.f, Q = 0.f;
#pragma unroll
    for (int j = 0; j < 8; ++j) { S += sp[j][gh]; Q += sq[j][gh]; }
    float mean = S * (1.0f / 32768.f);
    float var = Q * (1.0f / 32768.f) - mean * mean;
    float rstd = rsqrtf(var + 1e-5f);
    f32x4 ga4 = *(const f32x4*)(gamma + o4);
    f32x4 be4 = *(const f32x4*)(beta + o4);

    // ---- normalize from registers + swish, write f32 out ----
#pragma unroll
    for (int i = 0; i < 8; ++i) {
        int T = w + i * 8;
        float* ob = out + ((size_t)(b * Cn + o4)) * Nn + T * 64;
#pragma unroll
        for (int n4 = 0; n4 < 4; ++n4) {
#pragma unroll
            for (int r = 0; r < 4; ++r) {
                float hv = (tv[i][n4][r] - mean) * rstd * ga4[r] + be4[r];
                ob[(size_t)r * Nn + n4 * 16 + l15] = hv / (1.f + __expf(-hv));
            }
        }
    }
}

// ---------------- launcher ----------------
extern "C" void kernel_launch(void* const* d_in, const int* in_sizes, int n_in,
                              void* d_out, int out_size, void* d_ws, size_t ws_size,
                              hipStream_t stream) {
    (void)in_sizes; (void)n_in; (void)out_size; (void)ws_size;
    const float* x     = (const float*)d_in[0];
    const float* ctx   = (const float*)d_in[1];
    const float* qw    = (const float*)d_in[2];
    const float* qb    = (const float*)d_in[3];
    const float* kw    = (const float*)d_in[4];
    const float* vw    = (const float*)d_in[5];
    const float* ow    = (const float*)d_in[6];
    const float* ob    = (const float*)d_in[7];
    const float* gamma = (const float*)d_in[8];
    const float* beta  = (const float*)d_in[9];
    float* out = (float*)d_out;
    char* ws = (char*)d_ws;

    u16* wg   = (u16*)(ws + OFF_W);
    u16* kwb  = (u16*)(ws + OFF_KWB);
    u16* vwb  = (u16*)(ws + OFF_VWB);
    u16* ctxb = (u16*)(ws + OFF_CTXB);
    u16* kqp  = (u16*)(ws + OFF_KQ);
    u16* vop  = (u16*)(ws + OFF_VO);
    float* kqbp = (float*)(ws + OFF_KQB);
    u16* xbt  = (u16*)(ws + OFF_XBT);
    u16* kt   = (u16*)(ws + OFF_KT);
    u16* vc   = (u16*)(ws + OFF_V);
    u16* qwTb = (u16*)(ws + OFF_QWB);
    u16* owb  = (u16*)(ws + OFF_OWB);

    k_prepall<<<5568, 256, 0, stream>>>(x, xbt, qw, ow, kw, vw, ctx,
                                        qwTb, owb, kwb, vwb, ctxb);
    k_kv<<<dim3(4, Bn), 256, 0, stream>>>(kwb, vwb, ctxb, kt, vc);
    k_kqvo<<<dim3(8, Bn), 256, 0, stream>>>(kt, qwTb, owb, vc, qb, kqp, kqbp, vop);
    k_score<<<dim3(64, Bn), 256, 0, stream>>>(kqp, kqbp, xbt, wg);
    k_pass2<<<dim3(16, Bn), 512, 0, stream>>>(wg, vop, xbt, ob, gamma, beta, out);
}